// Round 1
// baseline (325.104 us; speedup 1.0000x reference)
//
#include <hip/hip_runtime.h>
#include <hip/hip_fp16.h>

typedef float f32x4 __attribute__((ext_vector_type(4)));
typedef __bf16 bf16x8 __attribute__((ext_vector_type(8)));

#define BB_ 8
#define TT_ 4096
#define DD_ 1024
#define MM_ (BB_*TT_)   // 32768
#define KK_ DD_         // 1024

#define BM 128
#define BN 128
#define BK 32

#define NCH 64
#define LCH (TT_/NCH)   // 64

static __device__ __forceinline__ unsigned short f2bf_rn(float f) {
  unsigned int u = __float_as_uint(f);
  u += 0x7FFFu + ((u >> 16) & 1u);
  return (unsigned short)(u >> 16);
}

// ---------------- conversion: f32 -> bf16 bits (vectorized) ----------------
__global__ void cvt_f32_bf16(const float4* __restrict__ src,
                             ushort4* __restrict__ dst, int n4) {
  int stride = gridDim.x * blockDim.x;
  for (int i = blockIdx.x * blockDim.x + threadIdx.x; i < n4; i += stride) {
    float4 v = src[i];
    ushort4 o;
    o.x = f2bf_rn(v.x); o.y = f2bf_rn(v.y);
    o.z = f2bf_rn(v.z); o.w = f2bf_rn(v.w);
    dst[i] = o;
  }
}

// ---------------- GEMM (m97 structure) + fused epilogue ----------------
__device__ __forceinline__ void gload_lds16(const void* g, void* l) {
  __builtin_amdgcn_global_load_lds(
      (const __attribute__((address_space(1))) void*)g,
      (__attribute__((address_space(3))) void*)l, 16, 0, 0);
}

__global__ __launch_bounds__(256) void gemm_fused(
    const unsigned short* __restrict__ Xb,  // [M][K] bf16 bits
    const unsigned short* __restrict__ Wb,  // [2048][K] bf16 bits (Wz;Wh)
    const float* __restrict__ bz, const float* __restrict__ bh,
    __half* __restrict__ Zb, __half* __restrict__ Gb) // each [M][1024]
{
  __shared__ __align__(16) unsigned short lA[BM * BK];
  __shared__ __align__(16) unsigned short lB[BN * BK];
  const int tid  = threadIdx.x;
  const int wave = tid >> 6;
  const int lane = tid & 63;
  const int m0 = blockIdx.x * BM;
  const int e0 = blockIdx.y * BN;   // 0..2047 in concat space
  const int wr = wave >> 1, wc = wave & 1;
  const int fr = lane & 15;  // fragment row/col index
  const int kg = lane >> 4;  // k-group 0..3

  f32x4 acc[4][4];
  #pragma unroll
  for (int i = 0; i < 4; i++)
    #pragma unroll
    for (int j = 0; j < 4; j++)
      acc[i][j] = (f32x4){0.f, 0.f, 0.f, 0.f};

  for (int kk = 0; kk < KK_; kk += BK) {
    // stage A,B tiles: linear LDS dest, 16B per lane, wave-uniform base
    #pragma unroll
    for (int it = 0; it < 2; ++it) {
      int il  = (wave * 2 + it) * 64 + lane;
      int row = il >> 2;          // 0..127
      int col = (il & 3) * 8;     // bf16 elems (16B chunks)
      gload_lds16(Xb + (size_t)(m0 + row) * KK_ + kk + col,
                  lA + (size_t)(wave * 2 + it) * 512);
      gload_lds16(Wb + (size_t)(e0 + row) * KK_ + kk + col,
                  lB + (size_t)(wave * 2 + it) * 512);
    }
    __syncthreads();   // drains vmcnt -> LDS tiles ready
    bf16x8 af[4], bfv[4];
    #pragma unroll
    for (int i = 0; i < 4; i++)
      af[i] = *reinterpret_cast<const bf16x8*>(&lA[(wr * 64 + i * 16 + fr) * BK + kg * 8]);
    #pragma unroll
    for (int j = 0; j < 4; j++)
      bfv[j] = *reinterpret_cast<const bf16x8*>(&lB[(wc * 64 + j * 16 + fr) * BK + kg * 8]);
    #pragma unroll
    for (int i = 0; i < 4; i++)
      #pragma unroll
      for (int j = 0; j < 4; j++)
        acc[i][j] = __builtin_amdgcn_mfma_f32_16x16x32_bf16(af[i], bfv[j], acc[i][j], 0, 0, 0);
    __syncthreads();   // all waves done reading before next-stage overwrite
  }

  // epilogue: bias + sigmoid (z-half) or g() (h-half), store fp16
  const bool isZ = (e0 < DD_);
  const float* bias = isZ ? bz : bh;
  __half* outp = isZ ? Zb : Gb;
  const int ec0 = isZ ? e0 : (e0 - DD_);
  #pragma unroll
  for (int j = 0; j < 4; j++) {
    int e = ec0 + wc * 64 + j * 16 + fr;
    float bv = bias[e];
    #pragma unroll
    for (int i = 0; i < 4; i++) {
      int mb = m0 + wr * 64 + i * 16 + kg * 4;
      f32x4 v = acc[i][j];
      #pragma unroll
      for (int r = 0; r < 4; r++) {
        float val = v[r] + bv;
        float res;
        if (isZ) {
          res = 1.0f / (1.0f + __expf(-val));            // z = sigmoid(k)
        } else {
          res = (val >= 0.0f) ? (val + 0.5f)             // g(th)
                              : (1.0f / (1.0f + __expf(-val)));
        }
        outp[(size_t)(mb + r) * DD_ + e] = __float2half(res);
      }
    }
  }
}

// ---------------- scan phase A: per-chunk (P,Q) ----------------
__global__ __launch_bounds__(256) void scan_partial(
    const ushort4* __restrict__ Z, const ushort4* __restrict__ G,
    float4* __restrict__ P, float4* __restrict__ Q) {
  const int d4 = threadIdx.x;   // 0..255 -> 4 dims each
  const int c  = blockIdx.x;    // chunk
  const int b  = blockIdx.y;    // batch
  size_t base = ((size_t)b * TT_ + (size_t)c * LCH) * (DD_ / 4) + d4;
  float p0=1.f,p1=1.f,p2=1.f,p3=1.f, q0=0.f,q1=0.f,q2=0.f,q3=0.f;
  for (int t = 0; t < LCH; ++t) {
    ushort4 uz = Z[base + (size_t)t * (DD_ / 4)];
    ushort4 ug = G[base + (size_t)t * (DD_ / 4)];
    float z, g, a;
    z = __half2float(__ushort_as_half(uz.x)); g = __half2float(__ushort_as_half(ug.x));
    a = 1.f - z; p0 *= a; q0 = fmaf(a, q0, z * g);
    z = __half2float(__ushort_as_half(uz.y)); g = __half2float(__ushort_as_half(ug.y));
    a = 1.f - z; p1 *= a; q1 = fmaf(a, q1, z * g);
    z = __half2float(__ushort_as_half(uz.z)); g = __half2float(__ushort_as_half(ug.z));
    a = 1.f - z; p2 *= a; q2 = fmaf(a, q2, z * g);
    z = __half2float(__ushort_as_half(uz.w)); g = __half2float(__ushort_as_half(ug.w));
    a = 1.f - z; p3 *= a; q3 = fmaf(a, q3, z * g);
  }
  size_t o = ((size_t)b * NCH + c) * (DD_ / 4) + d4;
  P[o] = make_float4(p0, p1, p2, p3);
  Q[o] = make_float4(q0, q1, q2, q3);
}

// ---------------- scan phase B: exclusive scan over chunks ----------------
__global__ __launch_bounds__(256) void scan_combine(
    const float4* __restrict__ P, const float4* __restrict__ Q,
    float4* __restrict__ H) {
  const int d4 = threadIdx.x;
  const int b  = blockIdx.x;
  float4 h = make_float4(0.f, 0.f, 0.f, 0.f);
  for (int c = 0; c < NCH; ++c) {
    size_t o = ((size_t)b * NCH + c) * (DD_ / 4) + d4;
    H[o] = h;
    float4 p = P[o], q = Q[o];
    h.x = fmaf(p.x, h.x, q.x);
    h.y = fmaf(p.y, h.y, q.y);
    h.z = fmaf(p.z, h.z, q.z);
    h.w = fmaf(p.w, h.w, q.w);
  }
}

// ---------------- scan phase C: apply + write output ----------------
__global__ __launch_bounds__(256) void scan_apply(
    const ushort4* __restrict__ Z, const ushort4* __restrict__ G,
    const float4* __restrict__ H, float4* __restrict__ out) {
  const int d4 = threadIdx.x;
  const int c  = blockIdx.x;
  const int b  = blockIdx.y;
  float4 h = H[((size_t)b * NCH + c) * (DD_ / 4) + d4];
  size_t base = ((size_t)b * TT_ + (size_t)c * LCH) * (DD_ / 4) + d4;
  for (int t = 0; t < LCH; ++t) {
    ushort4 uz = Z[base + (size_t)t * (DD_ / 4)];
    ushort4 ug = G[base + (size_t)t * (DD_ / 4)];
    float z, g, a;
    z = __half2float(__ushort_as_half(uz.x)); g = __half2float(__ushort_as_half(ug.x));
    a = 1.f - z; h.x = fmaf(a, h.x, z * g);
    z = __half2float(__ushort_as_half(uz.y)); g = __half2float(__ushort_as_half(ug.y));
    a = 1.f - z; h.y = fmaf(a, h.y, z * g);
    z = __half2float(__ushort_as_half(uz.z)); g = __half2float(__ushort_as_half(ug.z));
    a = 1.f - z; h.z = fmaf(a, h.z, z * g);
    z = __half2float(__ushort_as_half(uz.w)); g = __half2float(__ushort_as_half(ug.w));
    a = 1.f - z; h.w = fmaf(a, h.w, z * g);
    out[base + (size_t)t * (DD_ / 4)] = h;
  }
}

extern "C" void kernel_launch(void* const* d_in, const int* in_sizes, int n_in,
                              void* d_out, int out_size, void* d_ws, size_t ws_size,
                              hipStream_t stream) {
  const float* X  = (const float*)d_in[0];  // [8,4096,1024]
  const float* Wz = (const float*)d_in[1];  // [1024,1024]
  const float* bz = (const float*)d_in[2];
  const float* Wh = (const float*)d_in[3];
  const float* bh = (const float*)d_in[4];
  float* out = (float*)d_out;

  const size_t szXb = (size_t)MM_ * DD_ * 2;      // 64 MiB  bf16 X
  const size_t szWb = (size_t)2 * DD_ * DD_ * 2;  //  4 MiB  bf16 (Wz;Wh)
  const size_t szZ  = (size_t)MM_ * DD_ * 2;      // 64 MiB  fp16 each
  const size_t szPQ = (size_t)BB_ * NCH * DD_ * 4;//  2 MiB  each

  char* ws = (char*)d_ws;
  unsigned short *Xb, *Wb;
  __half *Zb, *Gb;
  const size_t needA = szXb + szWb + 2 * szZ + 3 * szPQ;
  if (ws_size >= needA) {
    Xb = (unsigned short*)ws;              ws += szXb;
    Wb = (unsigned short*)ws;              ws += szWb;
  } else {
    // fallback: stage X/W inside d_out (dead after GEMM), scan state in ws
    Xb = (unsigned short*)d_out;
    Wb = (unsigned short*)((char*)d_out + szXb);
  }
  Zb = (__half*)ws;  ws += szZ;
  Gb = (__half*)ws;  ws += szZ;
  float* P = (float*)ws;  ws += szPQ;
  float* Q = (float*)ws;  ws += szPQ;
  float* H = (float*)ws;

  // 1) convert inputs to bf16
  cvt_f32_bf16<<<2048, 256, 0, stream>>>((const float4*)X, (ushort4*)Xb,
                                         (int)((size_t)MM_ * DD_ / 4));
  cvt_f32_bf16<<<512, 256, 0, stream>>>((const float4*)Wz, (ushort4*)Wb,
                                        DD_ * DD_ / 4);
  cvt_f32_bf16<<<512, 256, 0, stream>>>((const float4*)Wh,
                                        (ushort4*)(Wb + (size_t)DD_ * DD_),
                                        DD_ * DD_ / 4);
  // 2) fused GEMM -> z, g  (N = 2048 concat)
  dim3 gg(MM_ / BM, (2 * DD_) / BN);
  gemm_fused<<<gg, 256, 0, stream>>>(Xb, Wb, bz, bh, Zb, Gb);

  // 3) chunked linear scan over T
  scan_partial<<<dim3(NCH, BB_), 256, 0, stream>>>((const ushort4*)Zb, (const ushort4*)Gb,
                                                   (float4*)P, (float4*)Q);
  scan_combine<<<BB_, 256, 0, stream>>>((const float4*)P, (const float4*)Q, (float4*)H);
  scan_apply<<<dim3(NCH, BB_), 256, 0, stream>>>((const ushort4*)Zb, (const ushort4*)Gb,
                                                 (const float4*)H, (float4*)out);
}